// Round 5
// baseline (296.639 us; speedup 1.0000x reference)
//
#include <hip/hip_runtime.h>

#define C_IN 32
#define C_OUT 64
#define BATCH 4
#define HH 128
#define WW 128
#define KK 7
#define PAD 3
#define TILE 16
#define HALO (TILE + KK - 1)   // 22
#define RSTRIDE 48             // 48 % 32 == 16 -> 8-lane b128 phases cover all 32 banks

// Weff layout: [C_IN][49][C_OUT]  (c, p = ky*7+kx, o) -> 100352 floats
// Beff: 64 floats right after Weff in d_ws.

// Merged prep: blocks 0..31 build Weff for input channel c = blockIdx.x;
// blocks 32..95 build Beff for output channel o = blockIdx.x - 32.
__global__ __launch_bounds__(256) void prep_all(
    const float* __restrict__ w3, const float* __restrict__ b3,
    const float* __restrict__ w5, const float* __restrict__ b5,
    const float* __restrict__ w7, const float* __restrict__ b7,
    const float* __restrict__ wf, const float* __restrict__ bf,
    float* __restrict__ Weff, float* __restrict__ Beff)
{
    const int tid = threadIdx.x;
    if (blockIdx.x < 32) {
        const int c = blockIdx.x;
        __shared__ float lwf[C_OUT * 49];
        __shared__ float lw3[9 * 9];
        __shared__ float lw5[16 * 25];
        __shared__ float lw7[24 * 49];

        for (int idx = tid; idx < C_OUT * 49; idx += 256) {
            int o = idx / 49, k = idx % 49;
            int j = (k < 9)  ? (c * 9 + k)
                  : (k < 25) ? (288 + c * 16 + (k - 9))
                             : (800 + c * 24 + (k - 25));
            lwf[idx] = wf[o * 1568 + j];
        }
        for (int idx = tid; idx < 81;   idx += 256) lw3[idx] = w3[c * 81 + idx];
        for (int idx = tid; idx < 400;  idx += 256) lw5[idx] = w5[c * 400 + idx];
        for (int idx = tid; idx < 1176; idx += 256) lw7[idx] = w7[c * 1176 + idx];
        __syncthreads();

        for (int idx = tid; idx < 49 * C_OUT; idx += 256) {
            int o = idx % C_OUT;        // o fastest -> coalesced store
            int p = idx / C_OUT;
            int ky = p / 7, kx = p % 7;
            float acc = 0.f;
            if (ky >= 2 && ky <= 4 && kx >= 2 && kx <= 4) {
                int pos = (ky - 2) * 3 + (kx - 2);
                #pragma unroll
                for (int k = 0; k < 9; ++k)
                    acc += lwf[o * 49 + k] * lw3[k * 9 + pos];
            }
            if (ky >= 1 && ky <= 5 && kx >= 1 && kx <= 5) {
                int pos = (ky - 1) * 5 + (kx - 1);
                #pragma unroll
                for (int k = 0; k < 16; ++k)
                    acc += lwf[o * 49 + 9 + k] * lw5[k * 25 + pos];
            }
            {
                int pos = ky * 7 + kx;
                #pragma unroll
                for (int k = 0; k < 24; ++k)
                    acc += lwf[o * 49 + 25 + k] * lw7[k * 49 + pos];
            }
            Weff[(c * 49 + p) * C_OUT + o] = acc;
        }
    } else {
        const int o = blockIdx.x - 32;
        float acc = 0.f;
        for (int j = tid; j < 1568; j += 256) {
            float bj = (j < 288) ? b3[j] : (j < 800) ? b5[j - 288] : b7[j - 800];
            acc += wf[o * 1568 + j] * bj;
        }
        __shared__ float red[256];
        red[tid] = acc;
        __syncthreads();
        for (int s = 128; s > 0; s >>= 1) {
            if (tid < s) red[tid] += red[tid + s];
            __syncthreads();
        }
        if (tid == 0) Beff[o] = red[0] + bf[o];
    }
}

// 512 threads = 8 waves; wave w owns output channels oc0 = 8w .. 8w+7.
// Lane: tx4 = lane&3 (4-px group), ty = lane>>2 (output row).
// Thread computes 4 px x 8 oc = 32 accumulators.
// Grid: (8, 8, BATCH) = 256 blocks -> exactly 1 block/CU (LDS 135 KB caps at 1).
__global__ __launch_bounds__(512, 2) void conv7(
    const float* __restrict__ x, const float* __restrict__ Weff,
    const float* __restrict__ Beff, float* __restrict__ out)
{
    __shared__ float xt[C_IN][HALO][RSTRIDE];   // 32*22*48*4 = 135168 B
    const int b  = blockIdx.z;
    const int h0 = blockIdx.y * TILE;
    const int w0 = blockIdx.x * TILE;
    const int tid = threadIdx.x;

    // Stage x tile (only cols 0..21 of each padded row are ever read).
    const float* xb = x + (size_t)b * C_IN * HH * WW;
    for (int idx = tid; idx < C_IN * HALO * HALO; idx += 512) {
        int row = idx / HALO;            // c*22 + r
        int col = idx - row * HALO;
        int c = row / HALO, r = row - c * HALO;
        int h = h0 + r - PAD, w = w0 + col - PAD;
        float v = 0.f;
        if (h >= 0 && h < HH && w >= 0 && w < WW)
            v = xb[(c * HH + h) * WW + w];
        xt[c][r][col] = v;
    }
    __syncthreads();

    const int tx4  = tid & 3;
    const int ty   = (tid >> 2) & 15;
    const int wave = __builtin_amdgcn_readfirstlane(tid >> 6);  // 0..7, wave-uniform
    const int oc0  = wave * 8;

    float acc[8][4] = {};                   // [o][px]
    const float* __restrict__ wbase = Weff + oc0;

    for (int c = 0; c < C_IN; ++c) {
        #pragma unroll
        for (int dy = 0; dy < 7; ++dy) {
            const float* xrow = &xt[c][ty + dy][tx4 * 4];
            float xr[10];
            *(float4*)(&xr[0]) = *(const float4*)(&xrow[0]);
            *(float4*)(&xr[4]) = *(const float4*)(&xrow[4]);
            *(float2*)(&xr[8]) = *(const float2*)(&xrow[8]);
            const float* __restrict__ wq = wbase + (c * 49 + dy * 7) * C_OUT;
            #pragma unroll
            for (int dx = 0; dx < 7; ++dx) {
                float wv[8];
                #pragma unroll
                for (int o = 0; o < 8; ++o) wv[o] = wq[dx * C_OUT + o];  // uniform -> s_load
                #pragma unroll
                for (int o = 0; o < 8; ++o)
                    #pragma unroll
                    for (int px = 0; px < 4; ++px)
                        acc[o][px] += xr[px + dx] * wv[o];
            }
        }
    }

    const int hh  = h0 + ty;
    const int wwb = w0 + tx4 * 4;
    #pragma unroll
    for (int o = 0; o < 8; ++o) {
        float bias = Beff[oc0 + o];
        float4 v;
        v.x = acc[o][0] + bias;
        v.y = acc[o][1] + bias;
        v.z = acc[o][2] + bias;
        v.w = acc[o][3] + bias;
        *(float4*)&out[(((size_t)b * C_OUT + oc0 + o) * HH + hh) * WW + wwb] = v;
    }
}

extern "C" void kernel_launch(void* const* d_in, const int* in_sizes, int n_in,
                              void* d_out, int out_size, void* d_ws, size_t ws_size,
                              hipStream_t stream) {
    const float* x  = (const float*)d_in[0];
    const float* w3 = (const float*)d_in[1];
    const float* b3 = (const float*)d_in[2];
    const float* w5 = (const float*)d_in[3];
    const float* b5 = (const float*)d_in[4];
    const float* w7 = (const float*)d_in[5];
    const float* b7 = (const float*)d_in[6];
    const float* wf = (const float*)d_in[7];
    const float* bf = (const float*)d_in[8];
    float* outp = (float*)d_out;

    float* Weff = (float*)d_ws;
    float* Beff = Weff + C_IN * 49 * C_OUT;

    prep_all<<<96, 256, 0, stream>>>(w3, b3, w5, b5, w7, b7, wf, bf, Weff, Beff);

    dim3 grid(WW / TILE, HH / TILE, BATCH);
    conv7<<<grid, 512, 0, stream>>>(x, Weff, Beff, outp);
}

// Round 6
// 113.624 us; speedup vs baseline: 2.6107x; 2.6107x over previous
//
#include <hip/hip_runtime.h>

#define BATCH 4
#define HH 128
#define WW 128

typedef __attribute__((ext_vector_type(8))) short bf16x8;
typedef __attribute__((ext_vector_type(4))) float f32x4;

__device__ __forceinline__ unsigned short f2bf(float f) {
    unsigned int u = __float_as_uint(f);
    unsigned int r = (u + 0x7FFFu + ((u >> 16) & 1u)) >> 16;   // RN-even
    return (unsigned short)r;
}

// Weff2 layout: [p=49][o=64][c=32] bf16 (c fastest).  Beff: 64 f32 after it.
// Merged prep: blocks 0..31 -> Weff2 for input channel c = blockIdx.x;
// blocks 32..95 -> Beff for output channel o = blockIdx.x - 32.
__global__ __launch_bounds__(256) void prep_all(
    const float* __restrict__ w3, const float* __restrict__ b3,
    const float* __restrict__ w5, const float* __restrict__ b5,
    const float* __restrict__ w7, const float* __restrict__ b7,
    const float* __restrict__ wf, const float* __restrict__ bf,
    unsigned short* __restrict__ Weff2, float* __restrict__ Beff)
{
    const int tid = threadIdx.x;
    if (blockIdx.x < 32) {
        const int c = blockIdx.x;
        __shared__ float lwf[64 * 49];
        __shared__ float lw3[9 * 9];
        __shared__ float lw5[16 * 25];
        __shared__ float lw7[24 * 49];

        for (int idx = tid; idx < 64 * 49; idx += 256) {
            int o = idx / 49, k = idx % 49;
            int j = (k < 9)  ? (c * 9 + k)
                  : (k < 25) ? (288 + c * 16 + (k - 9))
                             : (800 + c * 24 + (k - 25));
            lwf[idx] = wf[o * 1568 + j];
        }
        for (int idx = tid; idx < 81;   idx += 256) lw3[idx] = w3[c * 81 + idx];
        for (int idx = tid; idx < 400;  idx += 256) lw5[idx] = w5[c * 400 + idx];
        for (int idx = tid; idx < 1176; idx += 256) lw7[idx] = w7[c * 1176 + idx];
        __syncthreads();

        for (int idx = tid; idx < 49 * 64; idx += 256) {
            int o = idx % 64;
            int p = idx / 64;
            int ky = p / 7, kx = p % 7;
            float acc = 0.f;
            if (ky >= 2 && ky <= 4 && kx >= 2 && kx <= 4) {
                int pos = (ky - 2) * 3 + (kx - 2);
                #pragma unroll
                for (int k = 0; k < 9; ++k)
                    acc += lwf[o * 49 + k] * lw3[k * 9 + pos];
            }
            if (ky >= 1 && ky <= 5 && kx >= 1 && kx <= 5) {
                int pos = (ky - 1) * 5 + (kx - 1);
                #pragma unroll
                for (int k = 0; k < 16; ++k)
                    acc += lwf[o * 49 + 9 + k] * lw5[k * 25 + pos];
            }
            {
                int pos = ky * 7 + kx;
                #pragma unroll
                for (int k = 0; k < 24; ++k)
                    acc += lwf[o * 49 + 25 + k] * lw7[k * 49 + pos];
            }
            Weff2[(p * 64 + o) * 32 + c] = f2bf(acc);
        }
    } else {
        const int o = blockIdx.x - 32;
        float acc = 0.f;
        for (int j = tid; j < 1568; j += 256) {
            float bj = (j < 288) ? b3[j] : (j < 800) ? b5[j - 288] : b7[j - 800];
            acc += wf[o * 1568 + j] * bj;
        }
        __shared__ float red[256];
        red[tid] = acc;
        __syncthreads();
        for (int s = 128; s > 0; s >>= 1) {
            if (tid < s) red[tid] += red[tid + s];
            __syncthreads();
        }
        if (tid == 0) Beff[o] = red[0] + bf[o];
    }
}

// Implicit-GEMM conv via MFMA 16x16x32 bf16.
// Block: 256 thr = 4 waves, output tile 8 rows x 16 cols x 64 oc.
// Wave wid: oc-half = wid&1 (32 oc), row-group = wid>>1 (4 rows).
// LDS x tile: [14 rows][22 cols][32 ch] bf16, px stride padded to 17 words.
#define XROWS 14
#define XCOLS 22
#define PXW 17                       // words per pixel (16 + 1 pad)
#define NPX (XROWS * XCOLS)          // 308
#define LDSW (NPX * PXW)             // 5236 words = 20944 B

__global__ __launch_bounds__(256, 2) void conv_mfma(
    const float* __restrict__ x, const unsigned short* __restrict__ Weff2,
    const float* __restrict__ Beff, float* __restrict__ out)
{
    __shared__ unsigned int xw[LDSW];
    const int b  = blockIdx.z;
    const int h0 = blockIdx.y * 8;
    const int w0 = blockIdx.x * 16;
    const int tid = threadIdx.x;

    // ---- stage x tile: fp32 global (coalesced over cols) -> bf16x2 LDS ----
    const float* xb = x + (size_t)b * 32 * HH * WW;
    for (int e = tid; e < NPX * 16; e += 256) {
        int cp  = e / NPX;            // channel pair 0..15
        int pxl = e - cp * NPX;       // row*22+col
        int row = pxl / XCOLS, col = pxl - row * XCOLS;
        int h = h0 + row - 3, w = w0 + col - 3;
        float f0 = 0.f, f1 = 0.f;
        if (h >= 0 && h < HH && w >= 0 && w < WW) {
            f0 = xb[((2 * cp) * HH + h) * WW + w];
            f1 = xb[((2 * cp + 1) * HH + h) * WW + w];
        }
        xw[pxl * PXW + cp] = (unsigned int)f2bf(f0) | ((unsigned int)f2bf(f1) << 16);
    }
    __syncthreads();

    const int lane = tid & 63;
    const int n = lane & 15;          // free index: oc for A, px-col for B
    const int g = lane >> 4;          // k-group (8 channels)
    const int wid = __builtin_amdgcn_readfirstlane(tid >> 6);
    const int ocbase  = (wid & 1) * 32;
    const int row_grp = (wid >> 1) * 4;

    f32x4 acc[2][4];
    #pragma unroll
    for (int t = 0; t < 2; ++t)
        #pragma unroll
        for (int f = 0; f < 4; ++f)
            acc[t][f] = (f32x4){0.f, 0.f, 0.f, 0.f};

    const char* Wp = (const char*)Weff2;
    const int aoff0 = (ocbase + n) * 64 + g * 16;        // bytes within a p-slab
    const int aoff1 = aoff0 + 16 * 64;

    for (int ky = 0; ky < 7; ++ky) {
        #pragma unroll
        for (int kx = 0; kx < 7; ++kx) {
            const int p = ky * 7 + kx;
            bf16x8 a0 = *(const bf16x8*)(Wp + p * 4096 + aoff0);
            bf16x8 a1 = *(const bf16x8*)(Wp + p * 4096 + aoff1);
            #pragma unroll
            for (int f = 0; f < 4; ++f) {
                const int lrow = row_grp + f + ky;
                const int widx = (lrow * XCOLS + n + kx) * PXW + g * 4;
                bf16x8 bfrag = *(const bf16x8*)&xw[widx];
                acc[0][f] = __builtin_amdgcn_mfma_f32_16x16x32_bf16(
                    a0, bfrag, acc[0][f], 0, 0, 0);
                acc[1][f] = __builtin_amdgcn_mfma_f32_16x16x32_bf16(
                    a1, bfrag, acc[1][f], 0, 0, 0);
            }
        }
    }

    // ---- epilogue: D row = (lane>>4)*4 + reg (oc), col = lane&15 (px) ----
    const int oc_r = ocbase + g * 4;
    const int wcol = w0 + n;
    #pragma unroll
    for (int t = 0; t < 2; ++t) {
        #pragma unroll
        for (int r = 0; r < 4; ++r) {
            const int oc = oc_r + t * 16 + r;
            const float bias = Beff[oc];
            #pragma unroll
            for (int f = 0; f < 4; ++f) {
                const int h = h0 + row_grp + f;
                out[(((size_t)b * 64 + oc) * HH + h) * WW + wcol] =
                    acc[t][f][r] + bias;
            }
        }
    }
}

extern "C" void kernel_launch(void* const* d_in, const int* in_sizes, int n_in,
                              void* d_out, int out_size, void* d_ws, size_t ws_size,
                              hipStream_t stream) {
    const float* x  = (const float*)d_in[0];
    const float* w3 = (const float*)d_in[1];
    const float* b3 = (const float*)d_in[2];
    const float* w5 = (const float*)d_in[3];
    const float* b5 = (const float*)d_in[4];
    const float* w7 = (const float*)d_in[5];
    const float* b7 = (const float*)d_in[6];
    const float* wf = (const float*)d_in[7];
    const float* bf = (const float*)d_in[8];
    float* outp = (float*)d_out;

    unsigned short* Weff2 = (unsigned short*)d_ws;        // 49*64*32 bf16
    float* Beff = (float*)((char*)d_ws + 49 * 64 * 32 * sizeof(unsigned short));

    prep_all<<<96, 256, 0, stream>>>(w3, b3, w5, b5, w7, b7, wf, bf, Weff2, Beff);

    dim3 grid(WW / 16, HH / 8, BATCH);
    conv_mfma<<<grid, 256, 0, stream>>>(x, Weff2, Beff, outp);
}

// Round 13
// 107.609 us; speedup vs baseline: 2.7566x; 1.0559x over previous
//
#include <hip/hip_runtime.h>

#define BATCH 4
#define HH 128
#define WW 128

typedef __attribute__((ext_vector_type(8))) short bf16x8;
typedef __attribute__((ext_vector_type(4))) float f32x4;

__device__ __forceinline__ unsigned short f2bf(float f) {
    unsigned int u = __float_as_uint(f);
    unsigned int r = (u + 0x7FFFu + ((u >> 16) & 1u)) >> 16;   // RN-even
    return (unsigned short)r;
}

// ws layout:
//   xb16  [4][128][128][32] bf16 (channel-last)        : 4,194,304 B
//   Weff2 [p=49][o=64][c=32] bf16                      :   200,704 B
//   Beff  [64] f32                                     :       256 B

// prep: blocks 0..31   -> Weff2 slice for input channel c = blockIdx.x
//       blocks 32..95  -> Beff for output channel o = blockIdx.x - 32
//       blocks 96..607 -> x transpose for (b,h) row = blockIdx.x - 96
__global__ __launch_bounds__(256) void prep_all(
    const float* __restrict__ x,
    const float* __restrict__ w3, const float* __restrict__ b3,
    const float* __restrict__ w5, const float* __restrict__ b5,
    const float* __restrict__ w7, const float* __restrict__ b7,
    const float* __restrict__ wf, const float* __restrict__ bf,
    unsigned short* __restrict__ xb16,
    unsigned short* __restrict__ Weff2, float* __restrict__ Beff)
{
    const int tid = threadIdx.x;
    if (blockIdx.x < 32) {
        const int c = blockIdx.x;
        __shared__ float lwf[64 * 49];
        __shared__ float lw3[9 * 9];
        __shared__ float lw5[16 * 25];
        __shared__ float lw7[24 * 49];

        for (int idx = tid; idx < 64 * 49; idx += 256) {
            int o = idx / 49, k = idx % 49;
            int j = (k < 9)  ? (c * 9 + k)
                  : (k < 25) ? (288 + c * 16 + (k - 9))
                             : (800 + c * 24 + (k - 25));
            lwf[idx] = wf[o * 1568 + j];
        }
        for (int idx = tid; idx < 81;   idx += 256) lw3[idx] = w3[c * 81 + idx];
        for (int idx = tid; idx < 400;  idx += 256) lw5[idx] = w5[c * 400 + idx];
        for (int idx = tid; idx < 1176; idx += 256) lw7[idx] = w7[c * 1176 + idx];
        __syncthreads();

        for (int idx = tid; idx < 49 * 64; idx += 256) {
            int o = idx % 64;
            int p = idx / 64;
            int ky = p / 7, kx = p % 7;
            float acc = 0.f;
            if (ky >= 2 && ky <= 4 && kx >= 2 && kx <= 4) {
                int pos = (ky - 2) * 3 + (kx - 2);
                #pragma unroll
                for (int k = 0; k < 9; ++k)
                    acc += lwf[o * 49 + k] * lw3[k * 9 + pos];
            }
            if (ky >= 1 && ky <= 5 && kx >= 1 && kx <= 5) {
                int pos = (ky - 1) * 5 + (kx - 1);
                #pragma unroll
                for (int k = 0; k < 16; ++k)
                    acc += lwf[o * 49 + 9 + k] * lw5[k * 25 + pos];
            }
            {
                int pos = ky * 7 + kx;
                #pragma unroll
                for (int k = 0; k < 24; ++k)
                    acc += lwf[o * 49 + 25 + k] * lw7[k * 49 + pos];
            }
            Weff2[(p * 64 + o) * 32 + c] = f2bf(acc);
        }
    } else if (blockIdx.x < 96) {
        const int o = blockIdx.x - 32;
        float acc = 0.f;
        for (int j = tid; j < 1568; j += 256) {
            float bj = (j < 288) ? b3[j] : (j < 800) ? b5[j - 288] : b7[j - 800];
            acc += wf[o * 1568 + j] * bj;
        }
        __shared__ float red[256];
        red[tid] = acc;
        __syncthreads();
        for (int s = 128; s > 0; s >>= 1) {
            if (tid < s) red[tid] += red[tid + s];
            __syncthreads();
        }
        if (tid == 0) Beff[o] = red[0] + bf[o];
    } else {
        // transpose one (b,h) row: x[b][0..31][h][0..127] -> xb16[b][h][0..127][0..31]
        const int row = blockIdx.x - 96;       // 0..511
        const int b = row >> 7, h = row & 127;
        __shared__ float ls[32 * 129];         // [c][w], pad 129 vs bank conflicts
        const float* xr = x + ((size_t)(b * 32) * HH + h) * WW;
        for (int idx = tid; idx < 32 * 128; idx += 256) {
            int c = idx >> 7, w = idx & 127;
            ls[c * 129 + w] = xr[(size_t)c * HH * WW + w];
        }
        __syncthreads();
        unsigned int* dst = (unsigned int*)xb16 + ((size_t)(b * 128 + h) * 128) * 16;
        for (int wi = tid; wi < 2048; wi += 256) {
            int w = wi >> 4, cw = wi & 15;
            float f0 = ls[(2 * cw) * 129 + w];
            float f1 = ls[(2 * cw + 1) * 129 + w];
            dst[wi] = (unsigned int)f2bf(f0) | ((unsigned int)f2bf(f1) << 16);
        }
    }
}

// Implicit-GEMM conv via MFMA 16x16x32 bf16.
// Block: 512 thr = 8 waves; output tile 16 rows x 16 cols x 64 oc.
// Wave wid: oc-half = wid&1, row-quad = wid>>1 (4 rows each).
// LDS x tile: [22*22 px][32 ch] bf16 unpadded (uniform-bank for b128 r/w).
#define XROWS 22
#define XCOLS 22
#define NPX (XROWS * XCOLS)          // 484
typedef __attribute__((ext_vector_type(4))) unsigned int uint4v;

__global__ __launch_bounds__(512, 4) void conv_mfma(
    const unsigned short* __restrict__ xb16,
    const unsigned short* __restrict__ Weff2,
    const float* __restrict__ Beff, float* __restrict__ out)
{
    __shared__ unsigned int xw[NPX * 16];    // 30976 B
    const int b  = blockIdx.z;
    const int h0 = blockIdx.y * 16;
    const int w0 = blockIdx.x * 16;
    const int tid = threadIdx.x;

    // ---- stage: bf16 channel-last global -> LDS, 16B granules ----
    const uint4v* xbv = (const uint4v*)xb16 + (size_t)b * 128 * 128 * 4;
    const uint4v zero4 = (uint4v){0u, 0u, 0u, 0u};
    for (int e = tid; e < NPX * 4; e += 512) {
        int px = e >> 2, cg = e & 3;
        int row = px / XCOLS, col = px - row * XCOLS;
        int h = h0 + row - 3, w = w0 + col - 3;
        uint4v v = zero4;
        if (h >= 0 && h < HH && w >= 0 && w < WW)
            v = xbv[((h * WW + w) << 2) + cg];
        *(uint4v*)&xw[px * 16 + cg * 4] = v;
    }
    __syncthreads();

    const int lane = tid & 63;
    const int n = lane & 15;          // free index: oc for A, px-col for B
    const int g = lane >> 4;          // k-octet group
    const int wid = __builtin_amdgcn_readfirstlane(tid >> 6);
    const int ocbase  = (wid & 1) * 32;
    const int row_grp = (wid >> 1) * 4;

    f32x4 acc[2][4];
    #pragma unroll
    for (int t = 0; t < 2; ++t)
        #pragma unroll
        for (int f = 0; f < 4; ++f)
            acc[t][f] = (f32x4){0.f, 0.f, 0.f, 0.f};

    const char* Wp = (const char*)Weff2;
    const int aoff0 = (ocbase + n) * 64 + g * 16;        // bytes within a p-slab
    const int aoff1 = aoff0 + 16 * 64;

    for (int ky = 0; ky < 7; ++ky) {
        #pragma unroll
        for (int kx = 0; kx < 7; ++kx) {
            const int p = ky * 7 + kx;
            bf16x8 a0 = *(const bf16x8*)(Wp + p * 4096 + aoff0);
            bf16x8 a1 = *(const bf16x8*)(Wp + p * 4096 + aoff1);
            #pragma unroll
            for (int f = 0; f < 4; ++f) {
                const int lrow = row_grp + f + ky;
                const int widx = (lrow * XCOLS + n + kx) * 16 + g * 4;
                bf16x8 bfrag = *(const bf16x8*)&xw[widx];
                acc[0][f] = __builtin_amdgcn_mfma_f32_16x16x32_bf16(
                    a0, bfrag, acc[0][f], 0, 0, 0);
                acc[1][f] = __builtin_amdgcn_mfma_f32_16x16x32_bf16(
                    a1, bfrag, acc[1][f], 0, 0, 0);
            }
        }
    }

    // ---- epilogue: D row = (lane>>4)*4 + reg (oc), col = lane&15 (px) ----
    const int oc_r = ocbase + g * 4;
    const int wcol = w0 + n;
    #pragma unroll
    for (int t = 0; t < 2; ++t) {
        #pragma unroll
        for (int r = 0; r < 4; ++r) {
            const int oc = oc_r + t * 16 + r;
            const float bias = Beff[oc];
            #pragma unroll
            for (int f = 0; f < 4; ++f) {
                const int h = h0 + row_grp + f;
                out[(((size_t)b * 64 + oc) * HH + h) * WW + wcol] =
                    acc[t][f][r] + bias;
            }
        }
    }
}

extern "C" void kernel_launch(void* const* d_in, const int* in_sizes, int n_in,
                              void* d_out, int out_size, void* d_ws, size_t ws_size,
                              hipStream_t stream) {
    const float* x  = (const float*)d_in[0];
    const float* w3 = (const float*)d_in[1];
    const float* b3 = (const float*)d_in[2];
    const float* w5 = (const float*)d_in[3];
    const float* b5 = (const float*)d_in[4];
    const float* w7 = (const float*)d_in[5];
    const float* b7 = (const float*)d_in[6];
    const float* wf = (const float*)d_in[7];
    const float* bf = (const float*)d_in[8];
    float* outp = (float*)d_out;

    unsigned short* xb16  = (unsigned short*)d_ws;                   // 4,194,304 B
    unsigned short* Weff2 = (unsigned short*)((char*)d_ws + 4194304); // 200,704 B
    float*          Beff  = (float*)((char*)d_ws + 4194304 + 200704);

    prep_all<<<608, 256, 0, stream>>>(x, w3, b3, w5, b5, w7, b7, wf, bf,
                                      xb16, Weff2, Beff);

    dim3 grid(WW / 16, HH / 16, BATCH);
    conv_mfma<<<grid, 512, 0, stream>>>(xb16, Weff2, Beff, outp);
}